// Round 4
// baseline (170.070 us; speedup 1.0000x reference)
//
#include <hip/hip_runtime.h>
#include <hip/hip_bf16.h>
#include <math.h>

#define BATCH 8
#define NPTS 4096
#define CH 128
#define TILE 128

// exp(s/TEMP) = 2^(s * 10 * log2(e)). We fold sqrt(10*log2(e)) into the
// per-point normalize scale, so the GEMM accumulator is already the exp2
// argument and the epilogue exp is a single v_exp_f32.
#define SQRT_TEMP_LOG2E 3.79828256f   // sqrt(10 / ln(2)) = sqrt(14.4269504089)

typedef __attribute__((ext_vector_type(4))) float f32x4;
typedef __attribute__((ext_vector_type(8))) short bf16x8;

typedef __attribute__((address_space(3))) unsigned int lds_uint;
typedef __attribute__((address_space(1))) const unsigned int gbl_uint;

__device__ __forceinline__ void load_lds16(const void* g, const void* l) {
    __builtin_amdgcn_global_load_lds((gbl_uint*)g, (lds_uint*)l, 16, 0, 0);
}

// v_exp_f32 is 2^x. (__exp2f collides with a glibc math.h macro — R3 compile
// failure — so use the amdgcn builtin directly.)
__device__ __forceinline__ float fast_exp2(float x) {
    return __builtin_amdgcn_exp2f(x);
}

// ---------------------------------------------------------------------------
// Kernel 1: L2-normalize each point (column of features[b][:, n]) into bf16
// vn[b][n][c] (C contiguous), scaled by SQRT_TEMP_LOG2E, and zero pos/neg.
// 2 threads per point (half = 64 channels each): 65536 threads = 1024 waves
// = 4 waves/CU on all 256 CUs (R2's 1-thread/point ran 512 waves on half
// the CUs, latency-bound).
// ---------------------------------------------------------------------------
__global__ __launch_bounds__(256) void normalize_kernel(
    const float* __restrict__ f, __hip_bfloat16* __restrict__ vn,
    float* __restrict__ pos, float* __restrict__ neg)
{
    int idx = blockIdx.x * 256 + threadIdx.x;   // 0 .. 65535
    int point = idx >> 1, half = idx & 1;
    int b = point >> 12, n = point & (NPTS - 1);
    const float* base = f + (size_t)b * CH * NPTS + (size_t)(half * 64) * NPTS + n;

    float ss = 0.0f;
    #pragma unroll 8
    for (int c = 0; c < 64; c++) {
        float x = base[(size_t)c * NPTS];
        ss += x * x;
    }
    ss += __shfl_xor(ss, 1);                    // combine the two halves
    float scale = SQRT_TEMP_LOG2E / fmaxf(sqrtf(ss), 1e-12f);

    __hip_bfloat16* out = vn + (size_t)point * CH + half * 64;
    #pragma unroll
    for (int c0 = 0; c0 < 64; c0 += 8) {
        union { __hip_bfloat16 h[8]; uint4 u; } pk;
        #pragma unroll
        for (int j = 0; j < 8; j++)
            pk.h[j] = __float2bfloat16(base[(size_t)(c0 + j) * NPTS] * scale);
        *((uint4*)(out + c0)) = pk.u;
    }
    if (half == 0) pos[point] = 0.0f;
    else           neg[point] = 0.0f;
}

// ---------------------------------------------------------------------------
// Kernel 2 (symmetric): only tiles rt <= ct (528/1024 per batch); off-diag
// tiles feed both a row-side and a col-side reduction.
// Block = 512 threads (8 waves); wave w owns tile rows [w*16, w*16+16).
// B-tile staged in LDS via global_load_lds w/ XOR bank swizzle (R1/R2:
// SQ_LDS_BANK_CONFLICT == 0). A-fragments read straight from global
// (issued pre-barrier; latency hides behind the barrier wait) — LDS drops
// to ~41 KB -> 3 blocks/CU -> 24 waves/CU.
// ---------------------------------------------------------------------------
__global__ __launch_bounds__(512, 6) void tile_kernel(
    const __hip_bfloat16* __restrict__ vn, const int* __restrict__ labels,
    float* __restrict__ pos, float* __restrict__ neg)
{
    __shared__ short lB[TILE * CH];        // 32 KB
    __shared__ int labR[TILE], labC[TILE]; // 1 KB
    __shared__ float colT[8][TILE];        // 4 KB  per-wave col-sum partials
    __shared__ float colP[8][TILE];        // 4 KB

    const int b = blockIdx.z;

    // Linear pair index -> (rt, ct), rt <= ct.
    int t = blockIdx.x, rt = 0;
    while (t >= 32 - rt) { t -= 32 - rt; rt++; }
    const int ct = rt + t;
    const bool diag = (rt == ct);

    const int tid = threadIdx.x;
    const int w = tid >> 6, lane = tid & 63;
    const int lane15 = lane & 15, quad = lane >> 4;

    const int row0 = rt * TILE, col0 = ct * TILE;
    const __hip_bfloat16* Ab = vn + ((size_t)b * NPTS + row0) * CH;
    const __hip_bfloat16* Bb = vn + ((size_t)b * NPTS + col0) * CH;

    if (tid < 128)       labR[tid]       = labels[b * NPTS + row0 + tid];
    else if (tid < 256)  labC[tid - 128] = labels[b * NPTS + col0 + (tid - 128)];

    // B-tile -> LDS, XOR-swizzled at the global source (LDS dest order is
    // HW-fixed: wave-uniform base + lane*16B).
    #pragma unroll
    for (int i = 0; i < 4; i++) {
        int rsw = (i * 4 + quad) & 15;
        int g   = lane15 ^ rsw;
        int row = w * 16 + i * 4 + quad;
        int ldsrow = w * 16 + i * 4;          // wave-uniform
        load_lds16(Bb + (size_t)row * CH + g * 8, &lB[ldsrow * CH]);
    }

    // A-fragments from global: A[m][k], m = lane&15 (row), k-chunk = quad.
    // Issued before the barrier; __syncthreads' vmcnt(0) drain covers them.
    const __hip_bfloat16* Arow = Ab + (size_t)(w * 16 + lane15) * CH;
    bf16x8 afrag[4];
    #pragma unroll
    for (int ks = 0; ks < 4; ks++)
        afrag[ks] = *(const bf16x8*)(Arow + (ks * 4 + quad) * 8);

    __syncthreads();

    // MFMA: 16 rows x 128 cols per wave.
    f32x4 acc[8] = {};
    #pragma unroll
    for (int ks = 0; ks < 4; ks++) {
        int kg = ks * 4 + quad;
        int chunk = (kg ^ lane15) << 3;         // swizzled LDS offset (shorts)
        #pragma unroll
        for (int ni = 0; ni < 8; ni++) {
            bf16x8 bfrag = *(const bf16x8*)&lB[(ni * 16 + lane15) * CH + chunk];
            acc[ni] = __builtin_amdgcn_mfma_f32_16x16x32_bf16(
                afrag[ks], bfrag, acc[ni], 0, 0, 0);
        }
    }

    // Epilogue. C/D layout: col = lane&15, row = quad*4 + reg.
    int labc[8];
    #pragma unroll
    for (int ni = 0; ni < 8; ni++) labc[ni] = labC[ni * 16 + lane15];

    float tc[8] = {}, pc[8] = {};
    #pragma unroll
    for (int r = 0; r < 4; r++) {
        int row_l = w * 16 + quad * 4 + r;
        int lr = labR[row_l];
        float p = 0.0f, tt = 0.0f;
        if (diag) {
            #pragma unroll
            for (int ni = 0; ni < 8; ni++) {
                float e = fast_exp2(acc[ni][r]);
                if (row_l == ni * 16 + lane15) e = 0.0f;   // remove diagonal
                float em = (labc[ni] == lr) ? e : 0.0f;
                tt += e;  p += em;  tc[ni] += e;  pc[ni] += em;
            }
        } else {
            #pragma unroll
            for (int ni = 0; ni < 8; ni++) {
                float e = fast_exp2(acc[ni][r]);
                float em = (labc[ni] == lr) ? e : 0.0f;
                tt += e;  p += em;  tc[ni] += e;  pc[ni] += em;
            }
        }
        #pragma unroll
        for (int off = 1; off < 16; off <<= 1) {
            p  += __shfl_xor(p, off);
            tt += __shfl_xor(tt, off);
        }
        if (lane15 == 0) {
            atomicAdd(&pos[b * NPTS + row0 + row_l], p);
            atomicAdd(&neg[b * NPTS + row0 + row_l], tt - p);
        }
    }

    // Col-side: fold quads (16 rows/wave), stash per-wave partials, combine.
    if (!diag) {
        #pragma unroll
        for (int ni = 0; ni < 8; ni++) {
            tc[ni] += __shfl_xor(tc[ni], 16);  tc[ni] += __shfl_xor(tc[ni], 32);
            pc[ni] += __shfl_xor(pc[ni], 16);  pc[ni] += __shfl_xor(pc[ni], 32);
        }
        if (quad == 0) {
            #pragma unroll
            for (int ni = 0; ni < 8; ni++) {
                colT[w][ni * 16 + lane15] = tc[ni];
                colP[w][ni * 16 + lane15] = pc[ni];
            }
        }
    }
    __syncthreads();
    if (!diag && tid < 128) {
        float T = 0.0f, P = 0.0f;
        #pragma unroll
        for (int ww = 0; ww < 8; ww++) { T += colT[ww][tid]; P += colP[ww][tid]; }
        atomicAdd(&pos[b * NPTS + col0 + tid], P);
        atomicAdd(&neg[b * NPTS + col0 + tid], T - P);
    }
}

// ---------------------------------------------------------------------------
// Kernel 3: deviation_i = log((p+n)/p); mean over all 32768 rows == mean of
// per-cloud means (equal N). Single block, 1024 threads.
// ---------------------------------------------------------------------------
__global__ __launch_bounds__(1024) void finalize_kernel(
    const float* __restrict__ pos, const float* __restrict__ neg,
    float* __restrict__ out)
{
    float acc = 0.0f;
    for (int i = threadIdx.x; i < BATCH * NPTS; i += 1024) {
        float p = pos[i];
        float t = p + neg[i];
        acc += __logf(t / p);   // == -log(p / (p+n))  (worked in R2)
    }
    #pragma unroll
    for (int off = 32; off; off >>= 1) acc += __shfl_down(acc, off);
    __shared__ float red[16];
    if ((threadIdx.x & 63) == 0) red[threadIdx.x >> 6] = acc;
    __syncthreads();
    if (threadIdx.x < 16) {
        float v = red[threadIdx.x];
        #pragma unroll
        for (int off = 8; off; off >>= 1) v += __shfl_down(v, off);
        if (threadIdx.x == 0) out[0] = v * (1.0f / (BATCH * NPTS));
    }
}

extern "C" void kernel_launch(void* const* d_in, const int* in_sizes, int n_in,
                              void* d_out, int out_size, void* d_ws, size_t ws_size,
                              hipStream_t stream)
{
    const float* features = (const float*)d_in[0];
    const int*   labels   = (const int*)d_in[1];
    float*       out      = (float*)d_out;

    // Workspace: vn bf16 [8][4096][128] = 8 MB, then pos/neg fp32.
    __hip_bfloat16* vn = (__hip_bfloat16*)d_ws;
    float* pos = (float*)((char*)d_ws + (size_t)BATCH * NPTS * CH * sizeof(__hip_bfloat16));
    float* neg = pos + BATCH * NPTS;

    hipLaunchKernelGGL(normalize_kernel, dim3(BATCH * NPTS * 2 / 256), dim3(256), 0, stream,
                       features, vn, pos, neg);
    // 528 = 32*33/2 upper-triangular tile pairs per batch.
    hipLaunchKernelGGL(tile_kernel, dim3(528, 1, BATCH), dim3(512), 0, stream,
                       vn, labels, pos, neg);
    hipLaunchKernelGGL(finalize_kernel, dim3(1), dim3(1024), 0, stream, pos, neg, out);
}

// Round 5
// 143.633 us; speedup vs baseline: 1.1841x; 1.1841x over previous
//
#include <hip/hip_runtime.h>
#include <hip/hip_bf16.h>
#include <math.h>

#define BATCH 8
#define NPTS 4096
#define CH 128
#define TILE 128

// exp(s/TEMP) = 2^(s * 10 * log2(e)). sqrt(10/ln2) is folded into the
// normalize scale so the GEMM accumulator is already the exp2 argument.
#define SQRT_TEMP_LOG2E 3.79828256f   // sqrt(14.4269504089)

typedef __attribute__((ext_vector_type(4))) float f32x4;
typedef __attribute__((ext_vector_type(8))) short bf16x8;

typedef __attribute__((address_space(3))) unsigned int lds_uint;
typedef __attribute__((address_space(1))) const unsigned int gbl_uint;

__device__ __forceinline__ void load_lds16(const void* g, const void* l) {
    __builtin_amdgcn_global_load_lds((gbl_uint*)g, (lds_uint*)l, 16, 0, 0);
}

// v_exp_f32 is 2^x. (__exp2f collides with a glibc math.h macro.)
__device__ __forceinline__ float fast_exp2(float x) {
    return __builtin_amdgcn_exp2f(x);
}

// ---------------------------------------------------------------------------
// Kernel 1: one-pass L2-normalize. 4 threads/point, 32 channels each held in
// registers (single global read), sumsq combined via 2 shfl_xor steps.
// 131072 threads = 512 blocks = 2 blocks/CU. Also zeroes pos/neg.
// ---------------------------------------------------------------------------
__global__ __launch_bounds__(256) void normalize_kernel(
    const float* __restrict__ f, __hip_bfloat16* __restrict__ vn,
    float* __restrict__ pos, float* __restrict__ neg)
{
    int idx = blockIdx.x * 256 + threadIdx.x;   // 0 .. 131071
    int point = idx >> 2, q = idx & 3;
    int b = point >> 12, n = point & (NPTS - 1);
    const float* base = f + (size_t)b * CH * NPTS + (size_t)(q * 32) * NPTS + n;

    float x[32];
    float ss = 0.0f;
    #pragma unroll
    for (int c = 0; c < 32; c++) {
        x[c] = base[(size_t)c * NPTS];
        ss += x[c] * x[c];
    }
    ss += __shfl_xor(ss, 1);
    ss += __shfl_xor(ss, 2);    // 4 lanes of one point share ss
    float scale = SQRT_TEMP_LOG2E / fmaxf(sqrtf(ss), 1e-12f);

    __hip_bfloat16* out = vn + (size_t)point * CH + q * 32;
    #pragma unroll
    for (int c0 = 0; c0 < 32; c0 += 8) {
        union { __hip_bfloat16 h[8]; uint4 u; } pk;
        #pragma unroll
        for (int j = 0; j < 8; j++)
            pk.h[j] = __float2bfloat16(x[c0 + j] * scale);
        *((uint4*)(out + c0)) = pk.u;
    }
    if (q == 0) pos[point] = 0.0f;
    else if (q == 1) neg[point] = 0.0f;
}

__device__ __forceinline__ void decode_tri(int t, int& rt, int& ct) {
    rt = 0;
    while (t >= 32 - rt) { t -= 32 - rt; rt++; }
    ct = rt + t;
}

// ---------------------------------------------------------------------------
// Kernel 2: symmetric triangle (rt <= ct), TWO tiles per block {j, 527-j}
// (perfectly balanced), B-tile cross-tile double buffer: B(t1) prefetched
// via global_load_lds while tile 0 computes, so the barrier's vmcnt drain
// finds it landed. A-fragments direct from global (non-overlapping live
// ranges across tiles). launch_bounds(512,4): 128-VGPR cap — R4's (512,6)
// spilled ~80 B/thread (WRITE_SIZE 178 MB); do NOT tighten this again.
// LDS 74 KB -> 2 blocks/CU.
// ---------------------------------------------------------------------------
__global__ __launch_bounds__(512, 4) void tile_kernel(
    const __hip_bfloat16* __restrict__ vn, const int* __restrict__ labels,
    float* __restrict__ pos, float* __restrict__ neg)
{
    __shared__ short lB[2][TILE * CH];          // 64 KB
    __shared__ int   labR[2][TILE], labC[2][TILE]; // 2 KB
    __shared__ float colT[8][TILE], colP[8][TILE]; // 8 KB

    const int b = blockIdx.z;
    int rts[2], cts[2];
    decode_tri(blockIdx.x,       rts[0], cts[0]);
    decode_tri(527 - blockIdx.x, rts[1], cts[1]);

    const int tid = threadIdx.x;
    const int w = tid >> 6, lane = tid & 63;
    const int lane15 = lane & 15, quad = lane >> 4;
    const __hip_bfloat16* vb = vn + (size_t)b * NPTS * CH;

    // Labels for both tiles.
    if      (tid < 128) labR[0][tid]       = labels[b * NPTS + rts[0] * TILE + tid];
    else if (tid < 256) labC[0][tid - 128] = labels[b * NPTS + cts[0] * TILE + (tid - 128)];
    else if (tid < 384) labR[1][tid - 256] = labels[b * NPTS + rts[1] * TILE + (tid - 256)];
    else                labC[1][tid - 384] = labels[b * NPTS + cts[1] * TILE + (tid - 384)];

    // Stage B(t0) -> lB[0], XOR bank swizzle at the global source (LDS dest
    // order is HW-fixed: wave-uniform base + lane*16B). R1/R2: 0 conflicts.
    {
        const __hip_bfloat16* Bb = vb + (size_t)cts[0] * TILE * CH;
        #pragma unroll
        for (int i = 0; i < 4; i++) {
            int rsw = (i * 4 + quad) & 15;
            int g   = lane15 ^ rsw;
            int row = w * 16 + i * 4 + quad;
            int ldsrow = w * 16 + i * 4;
            load_lds16(Bb + (size_t)row * CH + g * 8, &lB[0][ldsrow * CH]);
        }
    }
    // A-fragments(t0): A[m][k], m = lane&15, k-chunk = quad (+4 per ks).
    bf16x8 afrag[4];
    {
        const __hip_bfloat16* Arow = vb + (size_t)(rts[0] * TILE + w * 16 + lane15) * CH;
        #pragma unroll
        for (int ks = 0; ks < 4; ks++)
            afrag[ks] = *(const bf16x8*)(Arow + (ks * 4 + quad) * 8);
    }
    __syncthreads();

    for (int it = 0; it < 2; it++) {
        const int rt = rts[it], ct = cts[it];
        const bool diag = (rt == ct);
        const int row0 = rt * TILE, col0 = ct * TILE;
        const short* curB = lB[it];

        if (it == 0) {
            // Prefetch B(t1) -> lB[1]; drains at the next barrier (after
            // ~MFMA+epilogue worth of cycles — hidden).
            const __hip_bfloat16* Bb = vb + (size_t)cts[1] * TILE * CH;
            #pragma unroll
            for (int i = 0; i < 4; i++) {
                int rsw = (i * 4 + quad) & 15;
                int g   = lane15 ^ rsw;
                int row = w * 16 + i * 4 + quad;
                int ldsrow = w * 16 + i * 4;
                load_lds16(Bb + (size_t)row * CH + g * 8, &lB[1][ldsrow * CH]);
            }
        }

        // MFMA: 16 rows x 128 cols per wave.
        f32x4 acc[8] = {};
        #pragma unroll
        for (int ks = 0; ks < 4; ks++) {
            int chunk = ((ks * 4 + quad) ^ lane15) << 3;
            #pragma unroll
            for (int ni = 0; ni < 8; ni++) {
                bf16x8 bfrag = *(const bf16x8*)&curB[(ni * 16 + lane15) * CH + chunk];
                acc[ni] = __builtin_amdgcn_mfma_f32_16x16x32_bf16(
                    afrag[ks], bfrag, acc[ni], 0, 0, 0);
            }
        }

        // Reload A for tile 1 now (live range of afrag(t0) just ended; the
        // ~500-cyc epilogue hides the load latency).
        if (it == 0) {
            const __hip_bfloat16* Arow = vb + (size_t)(rts[1] * TILE + w * 16 + lane15) * CH;
            #pragma unroll
            for (int ks = 0; ks < 4; ks++)
                afrag[ks] = *(const bf16x8*)(Arow + (ks * 4 + quad) * 8);
        }

        // Epilogue. C/D layout: col = lane&15, row = quad*4 + reg.
        int labc[8];
        #pragma unroll
        for (int ni = 0; ni < 8; ni++) labc[ni] = labC[it][ni * 16 + lane15];

        float tc[8] = {}, pc[8] = {};
        #pragma unroll
        for (int r = 0; r < 4; r++) {
            int row_l = w * 16 + quad * 4 + r;
            int lr = labR[it][row_l];
            float p = 0.0f, tt = 0.0f;
            if (diag) {
                #pragma unroll
                for (int ni = 0; ni < 8; ni++) {
                    float e = fast_exp2(acc[ni][r]);
                    if (row_l == ni * 16 + lane15) e = 0.0f;
                    float em = (labc[ni] == lr) ? e : 0.0f;
                    tt += e;  p += em;  tc[ni] += e;  pc[ni] += em;
                }
            } else {
                #pragma unroll
                for (int ni = 0; ni < 8; ni++) {
                    float e = fast_exp2(acc[ni][r]);
                    float em = (labc[ni] == lr) ? e : 0.0f;
                    tt += e;  p += em;  tc[ni] += e;  pc[ni] += em;
                }
            }
            #pragma unroll
            for (int off = 1; off < 16; off <<= 1) {
                p  += __shfl_xor(p, off);
                tt += __shfl_xor(tt, off);
            }
            if (lane15 == 0) {
                atomicAdd(&pos[b * NPTS + row0 + row_l], p);
                atomicAdd(&neg[b * NPTS + row0 + row_l], tt - p);
            }
        }

        // Col-side partials (off-diag tiles only).
        if (!diag) {
            #pragma unroll
            for (int ni = 0; ni < 8; ni++) {
                tc[ni] += __shfl_xor(tc[ni], 16);  tc[ni] += __shfl_xor(tc[ni], 32);
                pc[ni] += __shfl_xor(pc[ni], 16);  pc[ni] += __shfl_xor(pc[ni], 32);
            }
            if (quad == 0) {
                #pragma unroll
                for (int ni = 0; ni < 8; ni++) {
                    colT[w][ni * 16 + lane15] = tc[ni];
                    colP[w][ni * 16 + lane15] = pc[ni];
                }
            }
        }
        __syncthreads();   // partials visible; prefetch drained; buf[it] free
        if (!diag && tid < 128) {
            float T = 0.0f, P = 0.0f;
            #pragma unroll
            for (int ww = 0; ww < 8; ww++) { T += colT[ww][tid]; P += colP[ww][tid]; }
            atomicAdd(&pos[b * NPTS + col0 + tid], P);
            atomicAdd(&neg[b * NPTS + col0 + tid], T - P);
        }
        if (it == 0) __syncthreads();   // colT/colP free for tile 1
    }
}

// ---------------------------------------------------------------------------
// Kernel 3: mean of log((p+n)/p) over 32768 rows. Single block, 1024 thr.
// ---------------------------------------------------------------------------
__global__ __launch_bounds__(1024) void finalize_kernel(
    const float* __restrict__ pos, const float* __restrict__ neg,
    float* __restrict__ out)
{
    float acc = 0.0f;
    for (int i = threadIdx.x; i < BATCH * NPTS; i += 1024) {
        float p = pos[i];
        float t = p + neg[i];
        acc += __logf(t / p);   // == -log(p / (p+n))
    }
    #pragma unroll
    for (int off = 32; off; off >>= 1) acc += __shfl_down(acc, off);
    __shared__ float red[16];
    if ((threadIdx.x & 63) == 0) red[threadIdx.x >> 6] = acc;
    __syncthreads();
    if (threadIdx.x < 16) {
        float v = red[threadIdx.x];
        #pragma unroll
        for (int off = 8; off; off >>= 1) v += __shfl_down(v, off);
        if (threadIdx.x == 0) out[0] = v * (1.0f / (BATCH * NPTS));
    }
}

extern "C" void kernel_launch(void* const* d_in, const int* in_sizes, int n_in,
                              void* d_out, int out_size, void* d_ws, size_t ws_size,
                              hipStream_t stream)
{
    const float* features = (const float*)d_in[0];
    const int*   labels   = (const int*)d_in[1];
    float*       out      = (float*)d_out;

    __hip_bfloat16* vn = (__hip_bfloat16*)d_ws;
    float* pos = (float*)((char*)d_ws + (size_t)BATCH * NPTS * CH * sizeof(__hip_bfloat16));
    float* neg = pos + BATCH * NPTS;

    hipLaunchKernelGGL(normalize_kernel, dim3(BATCH * NPTS * 4 / 256), dim3(256), 0, stream,
                       features, vn, pos, neg);
    // 264 blocks/batch, each handling triangle tiles {j, 527-j}.
    hipLaunchKernelGGL(tile_kernel, dim3(264, 1, BATCH), dim3(512), 0, stream,
                       vn, labels, pos, neg);
    hipLaunchKernelGGL(finalize_kernel, dim3(1), dim3(1024), 0, stream, pos, neg, out);
}

// Round 6
// 136.945 us; speedup vs baseline: 1.2419x; 1.0488x over previous
//
#include <hip/hip_runtime.h>
#include <hip/hip_bf16.h>
#include <math.h>

#define BATCH 8
#define NPTS 4096
#define CH 128
#define TILE 128

// exp(s/TEMP) = 2^(s * 10 * log2(e)). sqrt(10/ln2) is folded into the
// normalize scale so the GEMM accumulator is already the exp2 argument.
#define SQRT_TEMP_LOG2E 3.79828256f   // sqrt(14.4269504089)

typedef __attribute__((ext_vector_type(4))) float f32x4;
typedef __attribute__((ext_vector_type(4))) int   i32x4;
typedef __attribute__((ext_vector_type(8))) short bf16x8;

typedef __attribute__((address_space(3))) unsigned int lds_uint;
typedef __attribute__((address_space(1))) const unsigned int gbl_uint;

__device__ __forceinline__ void load_lds16(const void* g, const void* l) {
    __builtin_amdgcn_global_load_lds((gbl_uint*)g, (lds_uint*)l, 16, 0, 0);
}

// v_exp_f32 is 2^x. (__exp2f collides with a glibc math.h macro.)
__device__ __forceinline__ float fast_exp2(float x) {
    return __builtin_amdgcn_exp2f(x);
}

// ---------------------------------------------------------------------------
// Kernel 1: one-pass L2-normalize. 4 threads/point, 32 channels each held in
// registers (single global read), sumsq combined via 2 shfl_xor steps.
// Also zeroes pos/neg. (Measured R1..R5: total-minus-tile is a constant
// ~75 us harness overhead, so this kernel is already off the critical path.)
// ---------------------------------------------------------------------------
__global__ __launch_bounds__(256) void normalize_kernel(
    const float* __restrict__ f, __hip_bfloat16* __restrict__ vn,
    float* __restrict__ pos, float* __restrict__ neg)
{
    int idx = blockIdx.x * 256 + threadIdx.x;   // 0 .. 131071
    int point = idx >> 2, q = idx & 3;
    int b = point >> 12, n = point & (NPTS - 1);
    const float* base = f + (size_t)b * CH * NPTS + (size_t)(q * 32) * NPTS + n;

    float x[32];
    float ss = 0.0f;
    #pragma unroll
    for (int c = 0; c < 32; c++) {
        x[c] = base[(size_t)c * NPTS];
        ss += x[c] * x[c];
    }
    ss += __shfl_xor(ss, 1);
    ss += __shfl_xor(ss, 2);    // 4 lanes of one point share ss
    float scale = SQRT_TEMP_LOG2E / fmaxf(sqrtf(ss), 1e-12f);

    __hip_bfloat16* out = vn + (size_t)point * CH + q * 32;
    #pragma unroll
    for (int c0 = 0; c0 < 32; c0 += 8) {
        union { __hip_bfloat16 h[8]; uint4 u; } pk;
        #pragma unroll
        for (int j = 0; j < 8; j++)
            pk.h[j] = __float2bfloat16(x[c0 + j] * scale);
        *((uint4*)(out + c0)) = pk.u;
    }
    if (q == 0) pos[point] = 0.0f;
    else if (q == 1) neg[point] = 0.0f;
}

// ---------------------------------------------------------------------------
// Kernel 2: full 32x32 tile grid, SWAPPED-operand MFMA epilogue.
//
// mfma(a,b,acc) maps the A-operand row to (quad*4+reg) and the B-operand row
// to lane15 in C/D. Both our fragments (A rows, B rows) have the identical
// per-lane layout (row = lane15, k = quad-chunk), so mfma(bfrag, afrag, acc)
// computes the transposed tile for free: lane15 = S-row, (quad,reg) = S-col.
// Each lane then reduces its 32 elements' pos/total IN REGISTERS; the only
// cross-lane work is 4 shfl_xor (fold 4 quads) + 2 atomics per 16 lanes.
// R2/R5's triangle scheme needed 64 shuffles/tile/wave (dependent
// ds_permute chains at 2.75 waves/SIMD = the measured 60% idle); full grid
// doubles MFMA (overlappable pipe) to kill that serialization.
//
// LDS: 32 KB B-tile + 0.5 KB labels -> with launch_bounds(512,6) (~85 VGPR
// cap; body needs ~70 — R4 showed a 64-cap spills) -> 3 blocks/CU, 24
// waves/CU vs R5's 16.
// ---------------------------------------------------------------------------
__global__ __launch_bounds__(512, 6) void tile_kernel(
    const __hip_bfloat16* __restrict__ vn, const int* __restrict__ labels,
    float* __restrict__ pos, float* __restrict__ neg)
{
    __shared__ short lB[TILE * CH];   // 32 KB
    __shared__ int labC[TILE];        // 0.5 KB

    const int b  = blockIdx.z;
    const int rt = blockIdx.y, ct = blockIdx.x;
    const bool diag = (rt == ct);

    const int tid = threadIdx.x;
    const int w = tid >> 6, lane = tid & 63;
    const int lane15 = lane & 15, quad = lane >> 4;

    const int row0 = rt * TILE, col0 = ct * TILE;
    const __hip_bfloat16* vb = vn + (size_t)b * NPTS * CH;

    if (tid < 128) labC[tid] = labels[b * NPTS + col0 + tid];

    // Stage B-tile -> LDS via global_load_lds, XOR bank swizzle at the
    // global source (LDS dest order is HW-fixed: wave-uniform base +
    // lane*16B). R1..R5: SQ_LDS_BANK_CONFLICT == 0 with this scheme.
    {
        const __hip_bfloat16* Bb = vb + (size_t)col0 * CH;
        #pragma unroll
        for (int i = 0; i < 4; i++) {
            int rsw = (i * 4 + quad) & 15;
            int g   = lane15 ^ rsw;
            int row = w * 16 + i * 4 + quad;
            int ldsrow = w * 16 + i * 4;          // wave-uniform
            load_lds16(Bb + (size_t)row * CH + g * 8, &lB[ldsrow * CH]);
        }
    }

    // A-fragments direct from global (L1/L2); latency hidden by the barrier.
    const int rowi = w * 16 + lane15;             // this lane's S-row (local)
    bf16x8 afrag[4];
    {
        const __hip_bfloat16* Arow = vb + (size_t)(row0 + rowi) * CH;
        #pragma unroll
        for (int ks = 0; ks < 4; ks++)
            afrag[ks] = *(const bf16x8*)(Arow + (ks * 4 + quad) * 8);
    }
    const int lr = labels[b * NPTS + row0 + rowi];  // row label (per-lane)

    __syncthreads();   // drains vmcnt (incl. global_load_lds)

    // MFMA, swapped operands: acc[ni] element (lane,reg) =
    //   S[row0 + w*16 + lane15][col0 + ni*16 + quad*4 + reg]
    f32x4 acc[8] = {};
    #pragma unroll
    for (int ks = 0; ks < 4; ks++) {
        int chunk = ((ks * 4 + quad) ^ lane15) << 3;
        #pragma unroll
        for (int ni = 0; ni < 8; ni++) {
            bf16x8 bfrag = *(const bf16x8*)&lB[(ni * 16 + lane15) * CH + chunk];
            acc[ni] = __builtin_amdgcn_mfma_f32_16x16x32_bf16(
                bfrag, afrag[ks], acc[ni], 0, 0, 0);
        }
    }

    // Epilogue: fully in-lane accumulation over this lane's 32 cols.
    float p = 0.0f, tt = 0.0f;
    if (diag) {
        #pragma unroll
        for (int ni = 0; ni < 8; ni++) {
            const i32x4 lc = *(const i32x4*)&labC[ni * 16 + quad * 4];
            const int jb = ni * 16 + quad * 4;
            #pragma unroll
            for (int r = 0; r < 4; r++) {
                float e = fast_exp2(acc[ni][r]);
                if (rowi == jb + r) e = 0.0f;       // remove diagonal
                tt += e;
                p  += (lc[r] == lr) ? e : 0.0f;
            }
        }
    } else {
        #pragma unroll
        for (int ni = 0; ni < 8; ni++) {
            const i32x4 lc = *(const i32x4*)&labC[ni * 16 + quad * 4];
            #pragma unroll
            for (int r = 0; r < 4; r++) {
                float e = fast_exp2(acc[ni][r]);
                tt += e;
                p  += (lc[r] == lr) ? e : 0.0f;
            }
        }
    }

    // Fold the 4 quads (same rows, different col ranges): 4 shuffles total.
    p  += __shfl_xor(p, 16);   p  += __shfl_xor(p, 32);
    tt += __shfl_xor(tt, 16);  tt += __shfl_xor(tt, 32);

    if (lane < 16) {
        atomicAdd(&pos[b * NPTS + row0 + rowi], p);
        atomicAdd(&neg[b * NPTS + row0 + rowi], tt - p);
    }
}

// ---------------------------------------------------------------------------
// Kernel 3: mean of log((p+n)/p) over 32768 rows. Single block, 1024 thr.
// ---------------------------------------------------------------------------
__global__ __launch_bounds__(1024) void finalize_kernel(
    const float* __restrict__ pos, const float* __restrict__ neg,
    float* __restrict__ out)
{
    float acc = 0.0f;
    for (int i = threadIdx.x; i < BATCH * NPTS; i += 1024) {
        float p = pos[i];
        float t = p + neg[i];
        acc += __logf(t / p);   // == -log(p / (p+n))
    }
    #pragma unroll
    for (int off = 32; off; off >>= 1) acc += __shfl_down(acc, off);
    __shared__ float red[16];
    if ((threadIdx.x & 63) == 0) red[threadIdx.x >> 6] = acc;
    __syncthreads();
    if (threadIdx.x < 16) {
        float v = red[threadIdx.x];
        #pragma unroll
        for (int off = 8; off; off >>= 1) v += __shfl_down(v, off);
        if (threadIdx.x == 0) out[0] = v * (1.0f / (BATCH * NPTS));
    }
}

extern "C" void kernel_launch(void* const* d_in, const int* in_sizes, int n_in,
                              void* d_out, int out_size, void* d_ws, size_t ws_size,
                              hipStream_t stream)
{
    const float* features = (const float*)d_in[0];
    const int*   labels   = (const int*)d_in[1];
    float*       out      = (float*)d_out;

    __hip_bfloat16* vn = (__hip_bfloat16*)d_ws;
    float* pos = (float*)((char*)d_ws + (size_t)BATCH * NPTS * CH * sizeof(__hip_bfloat16));
    float* neg = pos + BATCH * NPTS;

    hipLaunchKernelGGL(normalize_kernel, dim3(BATCH * NPTS * 4 / 256), dim3(256), 0, stream,
                       features, vn, pos, neg);
    // Full tile grid: 32x32 tiles per batch.
    hipLaunchKernelGGL(tile_kernel, dim3(NPTS / TILE, NPTS / TILE, BATCH), dim3(512), 0, stream,
                       vn, labels, pos, neg);
    hipLaunchKernelGGL(finalize_kernel, dim3(1), dim3(1024), 0, stream, pos, neg, out);
}